// Round 8
// baseline (155.602 us; speedup 1.0000x reference)
//
#include <hip/hip_runtime.h>

#define N_NODES 20000
#define N_EDGES 150000
#define FEAT 64
#define HEADS 8
#define N_RBF 20
#define COLS 1024   // 2 * HEADS * FEAT  (Q block then K block)

typedef __attribute__((ext_vector_type(8))) short short8;
typedef __attribute__((ext_vector_type(4))) float f32x4;

union frag_u { int4 i; short8 s; };

__device__ __forceinline__ unsigned short f2bf(float x) {
    unsigned int u = __float_as_uint(x);
    unsigned int r = (u + 0x7FFFu + ((u >> 16) & 1u)) >> 16;
    return (unsigned short)r;
}
__device__ __forceinline__ float fsilu(float x) {
    return x * __builtin_amdgcn_rcpf(1.0f + __expf(-x));
}

// ---------------------------------------------------------------------------
// K1 (MFMA, no LDS): qk[n][c] = bias[c] + sum_f W[c][f] x[n][f]  (bf16 out)
// Wave = 16 nodes x 64 cols. A = W rows, B = x rows; mirrored k-slot maps
// (lane g=lane>>4 holds k=8g..8g+7 for both operands - same convention the
// round-7 K2 validated). C: node = lane&15, cols = 4g+reg -> ushort4 store.
// grid = (4 col-groups of 256, 1250 node-tiles of 16), block = 256.
// ---------------------------------------------------------------------------
__global__ __launch_bounds__(256, 4) void qk_project_mfma(
    const float* __restrict__ x,
    const float* __restrict__ Wq, const float* __restrict__ bq,
    const float* __restrict__ Wk, const float* __restrict__ bk,
    unsigned short* __restrict__ qk)
{
    const int tid = threadIdx.x;
    const int lane = tid & 63;
    const int wv = tid >> 6;
    const int l15 = lane & 15;
    const int g = lane >> 4;

    const int colBase = blockIdx.x * 256 + wv * 64;   // global col of wave
    const int nodeBase = blockIdx.y * 16;             // 20000 = 1250*16 exact

    const bool isK = colBase >= 512;                  // uniform per block
    const float* W = isK ? Wk : Wq;
    const float* bias = isK ? bk : bq;
    const int colW = colBase & 511;

    // B-frags: x for 16 nodes (l15 = node), k-chunk 8g
    short8 bx[2];
#pragma unroll
    for (int s = 0; s < 2; ++s) {
        const float* p = x + (nodeBase + l15) * 64 + 32 * s + 8 * g;
        float4 v0 = *reinterpret_cast<const float4*>(p);
        float4 v1 = *reinterpret_cast<const float4*>(p + 4);
        frag_u f;
        f.i.x = f2bf(v0.x) | ((unsigned int)f2bf(v0.y) << 16);
        f.i.y = f2bf(v0.z) | ((unsigned int)f2bf(v0.w) << 16);
        f.i.z = f2bf(v1.x) | ((unsigned int)f2bf(v1.y) << 16);
        f.i.w = f2bf(v1.z) | ((unsigned int)f2bf(v1.w) << 16);
        bx[s] = f.s;
    }

    f32x4 acc[4];
#pragma unroll
    for (int c = 0; c < 4; ++c) acc[c] = (f32x4){0.f, 0.f, 0.f, 0.f};

#pragma unroll
    for (int c = 0; c < 4; ++c) {
#pragma unroll
        for (int s = 0; s < 2; ++s) {
            const float* p = W + (colW + 16 * c + l15) * 64 + 32 * s + 8 * g;
            float4 v0 = *reinterpret_cast<const float4*>(p);
            float4 v1 = *reinterpret_cast<const float4*>(p + 4);
            frag_u f;
            f.i.x = f2bf(v0.x) | ((unsigned int)f2bf(v0.y) << 16);
            f.i.y = f2bf(v0.z) | ((unsigned int)f2bf(v0.w) << 16);
            f.i.z = f2bf(v1.x) | ((unsigned int)f2bf(v1.y) << 16);
            f.i.w = f2bf(v1.z) | ((unsigned int)f2bf(v1.w) << 16);
            acc[c] = __builtin_amdgcn_mfma_f32_16x16x32_bf16(f.s, bx[s], acc[c], 0, 0, 0);
        }
    }

#pragma unroll
    for (int c = 0; c < 4; ++c) {
        float4 b4 = *reinterpret_cast<const float4*>(bias + colW + 16 * c + 4 * g);
        ushort4 sv;
        sv.x = f2bf(acc[c][0] + b4.x);
        sv.y = f2bf(acc[c][1] + b4.y);
        sv.z = f2bf(acc[c][2] + b4.z);
        sv.w = f2bf(acc[c][3] + b4.w);
        *reinterpret_cast<ushort4*>(
            qk + (size_t)(nodeBase + l15) * COLS + colBase + 16 * c + 4 * g) = sv;
    }
}

// ---------------------------------------------------------------------------
// K2 (MFMA): block = 64 edges, wave = head pair (h0 = 2*wv).
// Identical to round 7 except __launch_bounds__(256, 6): VGPR=64 <= 85 cap,
// waves/CU 12 -> 24 to hide the scattered q/k gather latency.
// ---------------------------------------------------------------------------
__global__ __launch_bounds__(256, 6) void edge_attn(
    const float* __restrict__ dist,
    const int* __restrict__ nbrs,      // [E][2]
    const float* __restrict__ Wdk,     // [8][64][20]
    const float* __restrict__ bdk,     // [8][64]
    const unsigned short* __restrict__ qk, // [N][1024] bf16
    float* __restrict__ out)           // [E][8]
{
    __shared__ int4 ef_s4[4][64];      // [kgroup][edge] : 8 bf16 each (4 KB)
    __shared__ int2 nbr_s[64];

    const int tid = threadIdx.x;
    const int lane = tid & 63;
    const int wv = tid >> 6;           // head pair
    const int h0 = wv * 2;
    const int l15 = lane & 15;
    const int g = lane >> 4;
    const int e0 = blockIdx.x * 64;

    // ---- persistent A-frags: W_dk for this head pair (+bias at k=20) ----
    short8 aw[8];
#pragma unroll
    for (int m = 0; m < 8; ++m) {
        int R = (h0 + (m >> 2)) * 64 + 16 * (m & 3) + l15;  // row of W_dk
        float w[8];
        if (g < 2) {
            const float* p = Wdk + R * 20 + 8 * g;
            float4 v0 = *reinterpret_cast<const float4*>(p);
            float4 v1 = *reinterpret_cast<const float4*>(p + 4);
            w[0]=v0.x; w[1]=v0.y; w[2]=v0.z; w[3]=v0.w;
            w[4]=v1.x; w[5]=v1.y; w[6]=v1.z; w[7]=v1.w;
        } else if (g == 2) {
            const float* p = Wdk + R * 20 + 16;
            float4 v0 = *reinterpret_cast<const float4*>(p);
            w[0]=v0.x; w[1]=v0.y; w[2]=v0.z; w[3]=v0.w;
            w[4]=bdk[R]; w[5]=0.0f; w[6]=0.0f; w[7]=0.0f;
        } else {
            w[0]=w[1]=w[2]=w[3]=w[4]=w[5]=w[6]=w[7]=0.0f;
        }
        frag_u f;
        f.i.x = f2bf(w[0]) | ((unsigned int)f2bf(w[1]) << 16);
        f.i.y = f2bf(w[2]) | ((unsigned int)f2bf(w[3]) << 16);
        f.i.z = f2bf(w[4]) | ((unsigned int)f2bf(w[5]) << 16);
        f.i.w = f2bf(w[6]) | ((unsigned int)f2bf(w[7]) << 16);
        aw[m] = f.s;
    }

    // ---- phase 1: wave 0 computes ef (bf16) + stashes nbrs ----
    if (tid < 64) {
        int e = e0 + lane;
        bool v = e < N_EDGES;
        float d = v ? dist[e] : 1.0f;
        int2 nn = make_int2(0, 0);
        if (v) nn = *reinterpret_cast<const int2*>(&nbrs[2 * e]);
        nbr_s[lane] = nn;

        float theta = 0.62831853071795864769f * d;   // pi*d/5
        float s1, c1;
        __sincosf(theta, &s1, &c1);
        float env = (d < 5.0f) ? 0.5f * (c1 + 1.0f) : 0.0f;
        float scale = env / d;

        float ef[N_RBF];
        float twoc = 2.0f * c1, sm1 = 0.0f, ss = s1;
#pragma unroll
        for (int r = 0; r < N_RBF; ++r) {
            ef[r] = ss * scale;
            float nx = twoc * ss - sm1;
            sm1 = ss; ss = nx;
        }
        unsigned int w[16];
#pragma unroll
        for (int q = 0; q < 10; ++q)
            w[q] = f2bf(ef[2*q]) | ((unsigned int)f2bf(ef[2*q+1]) << 16);
        w[10] = 0x3F80u;               // k=20 -> 1.0 (bias column), k=21 -> 0
        w[11] = w[12] = w[13] = w[14] = w[15] = 0u;
#pragma unroll
        for (int g2 = 0; g2 < 4; ++g2)
            ef_s4[g2][lane] = make_int4(w[4*g2], w[4*g2+1], w[4*g2+2], w[4*g2+3]);
    }
    __syncthreads();

    const char* qkb = reinterpret_cast<const char*>(qk);

#pragma unroll
    for (int t = 0; t < 4; ++t) {
        // B-frag: ef for 16 edges of this tile
        frag_u bf_;
        bf_.i = ef_s4[g][t * 16 + l15];

        // neighbor ids for this lane's edge
        int2 nn = nbr_s[t * 16 + l15];
        const char* bq = qkb + (size_t)nn.x * 2048 + h0 * 128 + 8 * g;
        const char* bk = qkb + (size_t)nn.y * 2048 + 1024 + h0 * 128 + 8 * g;
        uint2 qv[8], kv[8];
#pragma unroll
        for (int m = 0; m < 8; ++m) {
            qv[m] = *reinterpret_cast<const uint2*>(bq + 32 * m);
            kv[m] = *reinterpret_cast<const uint2*>(bk + 32 * m);
        }

        // dk pre-activation: 8 MFMAs (c-tiles) x K=32 (20 rbf + bias + pad)
        f32x4 acc[8];
#pragma unroll
        for (int m = 0; m < 8; ++m) {
            f32x4 z = {0.0f, 0.0f, 0.0f, 0.0f};
            acc[m] = __builtin_amdgcn_mfma_f32_16x16x32_bf16(aw[m], bf_.s, z, 0, 0, 0);
        }

        // contraction: sum_c q*k*silu(dk_pre) per head
        float tA = 0.0f, tB = 0.0f;
#pragma unroll
        for (int m = 0; m < 8; ++m) {
#pragma unroll
            for (int r2 = 0; r2 < 4; ++r2) {
                unsigned int qw = (r2 < 2) ? qv[m].x : qv[m].y;
                unsigned int kw = (r2 < 2) ? kv[m].x : kv[m].y;
                float qf = (r2 & 1) ? __uint_as_float(qw & 0xFFFF0000u)
                                    : __uint_as_float(qw << 16);
                float kf = (r2 & 1) ? __uint_as_float(kw & 0xFFFF0000u)
                                    : __uint_as_float(kw << 16);
                float dk = fsilu(acc[m][r2]);
                float p = qf * kf;
                if (m < 4) tA = fmaf(p, dk, tA);
                else       tB = fmaf(p, dk, tB);
            }
        }

        // reduce across the 4 lanes sharing this edge (l15 class)
        tA += __shfl_xor(tA, 16);
        tA += __shfl_xor(tA, 32);
        tB += __shfl_xor(tB, 16);
        tB += __shfl_xor(tB, 32);

        int e = e0 + t * 16 + l15;
        if (lane < 16 && e < N_EDGES) {
            float2 o = make_float2(fsilu(tA), fsilu(tB));
            *reinterpret_cast<float2*>(out + (size_t)e * 8 + h0) = o;
        }
    }
}

extern "C" void kernel_launch(void* const* d_in, const int* in_sizes, int n_in,
                              void* d_out, int out_size, void* d_ws, size_t ws_size,
                              hipStream_t stream) {
    const float* dist = (const float*)d_in[0];
    const int* nbrs   = (const int*)d_in[1];
    const float* x_i  = (const float*)d_in[2];
    const float* W_q  = (const float*)d_in[3];
    const float* b_q  = (const float*)d_in[4];
    const float* W_k  = (const float*)d_in[5];
    const float* b_k  = (const float*)d_in[6];
    const float* W_dk = (const float*)d_in[7];
    const float* b_dk = (const float*)d_in[8];
    float* out = (float*)d_out;

    unsigned short* qkbuf = (unsigned short*)d_ws;  // 20000*1024 bf16 = 41 MB

    dim3 g1(4, N_NODES / 16);   // 4 col-groups x 1250 node-tiles
    qk_project_mfma<<<g1, 256, 0, stream>>>(x_i, W_q, b_q, W_k, b_k, qkbuf);

    const int nb = (N_EDGES + 63) / 64;   // 2344 blocks, 64 edges each
    edge_attn<<<nb, 256, 0, stream>>>(dist, nbrs, W_dk, b_dk, qkbuf, out);
}

// Round 9
// 122.073 us; speedup vs baseline: 1.2747x; 1.2747x over previous
//
#include <hip/hip_runtime.h>

#define N_NODES 20000
#define N_EDGES 150000
#define FEAT 64
#define HEADS 8
#define N_RBF 20
#define COLS 1024   // 2 * HEADS * FEAT  (Q block then K block)

typedef __attribute__((ext_vector_type(8))) short short8;
typedef __attribute__((ext_vector_type(4))) float f32x4;

union frag_u { int4 i; short8 s; };

__device__ __forceinline__ unsigned short f2bf(float x) {
    unsigned int u = __float_as_uint(x);
    unsigned int r = (u + 0x7FFFu + ((u >> 16) & 1u)) >> 16;
    return (unsigned short)r;
}
__device__ __forceinline__ float fsilu(float x) {
    return x * __builtin_amdgcn_rcpf(1.0f + __expf(-x));
}

// ---------------------------------------------------------------------------
// K1 (MFMA, no LDS, W persistent): wave = 64 cols; loops 8 node-tiles/block.
// A = W rows (loaded once), B = x rows, mirrored k-slot maps (validated r8).
// grid = (4 col-groups, 157 node-chunks of 8x16 nodes), block = 256.
// ---------------------------------------------------------------------------
__global__ __launch_bounds__(256, 4) void qk_project_mfma(
    const float* __restrict__ x,
    const float* __restrict__ Wq, const float* __restrict__ bq,
    const float* __restrict__ Wk, const float* __restrict__ bk,
    unsigned short* __restrict__ qk)
{
    const int tid = threadIdx.x;
    const int lane = tid & 63;
    const int wv = tid >> 6;
    const int l15 = lane & 15;
    const int g = lane >> 4;

    const int colBase = blockIdx.x * 256 + wv * 64;   // global col of wave
    const bool isK = colBase >= 512;
    const float* W = isK ? Wk : Wq;
    const float* bias = isK ? bk : bq;
    const int colW = colBase & 511;

    // persistent A-frags: W rows for this wave's 64 cols (32 VGPRs)
    short8 aw[4][2];
#pragma unroll
    for (int c = 0; c < 4; ++c) {
#pragma unroll
        for (int s = 0; s < 2; ++s) {
            const float* p = W + (colW + 16 * c + l15) * 64 + 32 * s + 8 * g;
            float4 v0 = *reinterpret_cast<const float4*>(p);
            float4 v1 = *reinterpret_cast<const float4*>(p + 4);
            frag_u f;
            f.i.x = f2bf(v0.x) | ((unsigned int)f2bf(v0.y) << 16);
            f.i.y = f2bf(v0.z) | ((unsigned int)f2bf(v0.w) << 16);
            f.i.z = f2bf(v1.x) | ((unsigned int)f2bf(v1.y) << 16);
            f.i.w = f2bf(v1.z) | ((unsigned int)f2bf(v1.w) << 16);
            aw[c][s] = f.s;
        }
    }
    float4 b4[4];
#pragma unroll
    for (int c = 0; c < 4; ++c)
        b4[c] = *reinterpret_cast<const float4*>(bias + colW + 16 * c + 4 * g);

    for (int i = 0; i < 8; ++i) {
        int nt = blockIdx.y * 8 + i;
        if (nt >= N_NODES / 16) break;
        int nodeBase = nt * 16;

        short8 bx[2];
#pragma unroll
        for (int s = 0; s < 2; ++s) {
            const float* p = x + (nodeBase + l15) * 64 + 32 * s + 8 * g;
            float4 v0 = *reinterpret_cast<const float4*>(p);
            float4 v1 = *reinterpret_cast<const float4*>(p + 4);
            frag_u f;
            f.i.x = f2bf(v0.x) | ((unsigned int)f2bf(v0.y) << 16);
            f.i.y = f2bf(v0.z) | ((unsigned int)f2bf(v0.w) << 16);
            f.i.z = f2bf(v1.x) | ((unsigned int)f2bf(v1.y) << 16);
            f.i.w = f2bf(v1.z) | ((unsigned int)f2bf(v1.w) << 16);
            bx[s] = f.s;
        }

#pragma unroll
        for (int c = 0; c < 4; ++c) {
            f32x4 acc = {0.f, 0.f, 0.f, 0.f};
#pragma unroll
            for (int s = 0; s < 2; ++s)
                acc = __builtin_amdgcn_mfma_f32_16x16x32_bf16(aw[c][s], bx[s], acc, 0, 0, 0);
            ushort4 sv;
            sv.x = f2bf(acc[0] + b4[c].x);
            sv.y = f2bf(acc[1] + b4[c].y);
            sv.z = f2bf(acc[2] + b4[c].z);
            sv.w = f2bf(acc[3] + b4[c].w);
            *reinterpret_cast<ushort4*>(
                qk + (size_t)(nodeBase + l15) * COLS + colBase + 16 * c + 4 * g) = sv;
        }
    }
}

// ---------------------------------------------------------------------------
// K2 (MFMA + gather pipeline): block = 64 edges, wave = head pair.
// Double-buffered q/k gathers across the 4 edge-tiles: tile t+1's 32 loads
// issue before tile t's compute, hiding L3 gather latency under MFMA+silu.
// Per-m contraction keeps acc in 4 regs -> peak ~120 VGPR, (256,4) no spill.
// ---------------------------------------------------------------------------
__global__ __launch_bounds__(256, 4) void edge_attn(
    const float* __restrict__ dist,
    const int* __restrict__ nbrs,      // [E][2]
    const float* __restrict__ Wdk,     // [8][64][20]
    const float* __restrict__ bdk,     // [8][64]
    const unsigned short* __restrict__ qk, // [N][1024] bf16
    float* __restrict__ out)           // [E][8]
{
    __shared__ int4 ef_s4[4][64];      // [kgroup][edge] : 8 bf16 each (4 KB)
    __shared__ int2 nbr_s[64];

    const int tid = threadIdx.x;
    const int lane = tid & 63;
    const int wv = tid >> 6;           // head pair
    const int h0 = wv * 2;
    const int l15 = lane & 15;
    const int g = lane >> 4;
    const int e0 = blockIdx.x * 64;

    // ---- persistent A-frags: W_dk for this head pair (+bias at k=20) ----
    short8 aw[8];
#pragma unroll
    for (int m = 0; m < 8; ++m) {
        int R = (h0 + (m >> 2)) * 64 + 16 * (m & 3) + l15;  // row of W_dk
        float w[8];
        if (g < 2) {
            const float* p = Wdk + R * 20 + 8 * g;
            float4 v0 = *reinterpret_cast<const float4*>(p);
            float4 v1 = *reinterpret_cast<const float4*>(p + 4);
            w[0]=v0.x; w[1]=v0.y; w[2]=v0.z; w[3]=v0.w;
            w[4]=v1.x; w[5]=v1.y; w[6]=v1.z; w[7]=v1.w;
        } else if (g == 2) {
            const float* p = Wdk + R * 20 + 16;
            float4 v0 = *reinterpret_cast<const float4*>(p);
            w[0]=v0.x; w[1]=v0.y; w[2]=v0.z; w[3]=v0.w;
            w[4]=bdk[R]; w[5]=0.0f; w[6]=0.0f; w[7]=0.0f;
        } else {
            w[0]=w[1]=w[2]=w[3]=w[4]=w[5]=w[6]=w[7]=0.0f;
        }
        frag_u f;
        f.i.x = f2bf(w[0]) | ((unsigned int)f2bf(w[1]) << 16);
        f.i.y = f2bf(w[2]) | ((unsigned int)f2bf(w[3]) << 16);
        f.i.z = f2bf(w[4]) | ((unsigned int)f2bf(w[5]) << 16);
        f.i.w = f2bf(w[6]) | ((unsigned int)f2bf(w[7]) << 16);
        aw[m] = f.s;
    }

    // ---- phase 1: wave 0 computes ef (bf16) + stashes nbrs ----
    if (tid < 64) {
        int e = e0 + lane;
        bool v = e < N_EDGES;
        float d = v ? dist[e] : 1.0f;
        int2 nn = make_int2(0, 0);
        if (v) nn = *reinterpret_cast<const int2*>(&nbrs[2 * e]);
        nbr_s[lane] = nn;

        float theta = 0.62831853071795864769f * d;   // pi*d/5
        float s1, c1;
        __sincosf(theta, &s1, &c1);
        float env = (d < 5.0f) ? 0.5f * (c1 + 1.0f) : 0.0f;
        float scale = env / d;

        float ef[N_RBF];
        float twoc = 2.0f * c1, sm1 = 0.0f, ss = s1;
#pragma unroll
        for (int r = 0; r < N_RBF; ++r) {
            ef[r] = ss * scale;
            float nx = twoc * ss - sm1;
            sm1 = ss; ss = nx;
        }
        unsigned int w[16];
#pragma unroll
        for (int q = 0; q < 10; ++q)
            w[q] = f2bf(ef[2*q]) | ((unsigned int)f2bf(ef[2*q+1]) << 16);
        w[10] = 0x3F80u;               // k=20 -> 1.0 (bias column), k=21 -> 0
        w[11] = w[12] = w[13] = w[14] = w[15] = 0u;
#pragma unroll
        for (int g2 = 0; g2 < 4; ++g2)
            ef_s4[g2][lane] = make_int4(w[4*g2], w[4*g2+1], w[4*g2+2], w[4*g2+3]);
    }
    __syncthreads();

    const char* qkb = reinterpret_cast<const char*>(qk);

    uint2 qv[2][8], kv[2][8];
    // prologue: issue tile 0's gathers
    {
        int2 nn = nbr_s[l15];
        const char* bq = qkb + (size_t)nn.x * 2048 + h0 * 128 + 8 * g;
        const char* bk = qkb + (size_t)nn.y * 2048 + 1024 + h0 * 128 + 8 * g;
#pragma unroll
        for (int m = 0; m < 8; ++m) {
            qv[0][m] = *reinterpret_cast<const uint2*>(bq + 32 * m);
            kv[0][m] = *reinterpret_cast<const uint2*>(bk + 32 * m);
        }
    }

#pragma unroll
    for (int t = 0; t < 4; ++t) {
        const int cur = t & 1;
        // issue next tile's gathers before computing this one
        if (t < 3) {
            int2 nn = nbr_s[(t + 1) * 16 + l15];
            const char* bq = qkb + (size_t)nn.x * 2048 + h0 * 128 + 8 * g;
            const char* bk = qkb + (size_t)nn.y * 2048 + 1024 + h0 * 128 + 8 * g;
#pragma unroll
            for (int m = 0; m < 8; ++m) {
                qv[cur ^ 1][m] = *reinterpret_cast<const uint2*>(bq + 32 * m);
                kv[cur ^ 1][m] = *reinterpret_cast<const uint2*>(bk + 32 * m);
            }
        }

        frag_u bf_;
        bf_.i = ef_s4[g][t * 16 + l15];

        float tA = 0.0f, tB = 0.0f;
#pragma unroll
        for (int m = 0; m < 8; ++m) {
            f32x4 z = {0.0f, 0.0f, 0.0f, 0.0f};
            f32x4 acc = __builtin_amdgcn_mfma_f32_16x16x32_bf16(aw[m], bf_.s, z, 0, 0, 0);
#pragma unroll
            for (int r2 = 0; r2 < 4; ++r2) {
                unsigned int qw = (r2 < 2) ? qv[cur][m].x : qv[cur][m].y;
                unsigned int kw = (r2 < 2) ? kv[cur][m].x : kv[cur][m].y;
                float qf = (r2 & 1) ? __uint_as_float(qw & 0xFFFF0000u)
                                    : __uint_as_float(qw << 16);
                float kf = (r2 & 1) ? __uint_as_float(kw & 0xFFFF0000u)
                                    : __uint_as_float(kw << 16);
                float dk = fsilu(acc[r2]);
                float p = qf * kf;
                if (m < 4) tA = fmaf(p, dk, tA);
                else       tB = fmaf(p, dk, tB);
            }
        }

        // reduce across the 4 lanes sharing this edge (l15 class)
        tA += __shfl_xor(tA, 16);
        tA += __shfl_xor(tA, 32);
        tB += __shfl_xor(tB, 16);
        tB += __shfl_xor(tB, 32);

        int e = e0 + t * 16 + l15;
        if (lane < 16 && e < N_EDGES) {
            float2 o = make_float2(fsilu(tA), fsilu(tB));
            *reinterpret_cast<float2*>(out + (size_t)e * 8 + h0) = o;
        }
    }
}

extern "C" void kernel_launch(void* const* d_in, const int* in_sizes, int n_in,
                              void* d_out, int out_size, void* d_ws, size_t ws_size,
                              hipStream_t stream) {
    const float* dist = (const float*)d_in[0];
    const int* nbrs   = (const int*)d_in[1];
    const float* x_i  = (const float*)d_in[2];
    const float* W_q  = (const float*)d_in[3];
    const float* b_q  = (const float*)d_in[4];
    const float* W_k  = (const float*)d_in[5];
    const float* b_k  = (const float*)d_in[6];
    const float* W_dk = (const float*)d_in[7];
    const float* b_dk = (const float*)d_in[8];
    float* out = (float*)d_out;

    unsigned short* qkbuf = (unsigned short*)d_ws;  // 20000*1024 bf16 = 41 MB

    dim3 g1(4, (N_NODES / 16 + 7) / 8);   // 4 col-groups x 157 node-chunks
    qk_project_mfma<<<g1, 256, 0, stream>>>(x_i, W_q, b_q, W_k, b_k, qkbuf);

    const int nb = (N_EDGES + 63) / 64;   // 2344 blocks, 64 edges each
    edge_attn<<<nb, 256, 0, stream>>>(dist, nbrs, W_dk, b_dk, qkbuf, out);
}